// Round 3
// baseline (207.468 us; speedup 1.0000x reference)
//
#include <hip/hip_runtime.h>
#include <hip/hip_bf16.h>

// Chunked simple-GLA forward, B=2 H=32 T=4096 K=V=128, BT=64.
// grid = 64 (b,h) x 4 v-segments, 512 threads (8 waves).
// State slice S [128 kd x 32 vc] lives in MFMA accumulators.
// 2-phase / 2-raw-barrier pipeline, q/k/vT double-buffered in LDS.

#define BT 64
#define KD 128
#define VD 128
#define VSG 32
#define NCHUNK 64
#define TLEN 4096
#define SCALE 0.08838834764831845f   // 128^-0.5

#define QSTR 136   // q_s/k_s row stride
#define KWSTR 72   // kwT row stride (row = kd, 64 t + pad), XOR-swizzled
#define SHSTR 72   // s-hat row stride
#define SVSTR 136  // svt (h_n slice, [vc][kd]) row stride
#define VTSTR 72   // vT row stride (row = vc, 64 t + pad), XOR-swizzled

typedef __bf16 bf16;
typedef __bf16 bf16x8 __attribute__((ext_vector_type(8)));
typedef __bf16 bf16x4 __attribute__((ext_vector_type(4)));
typedef float f32x4 __attribute__((ext_vector_type(4)));

#define MFMA __builtin_amdgcn_mfma_f32_16x16x32_bf16

// Raw barrier: drain LDS ops only; global loads/stores stay in flight.
#define LGKM_BARRIER() do { asm volatile("s_waitcnt lgkmcnt(0)" ::: "memory"); \
                            __builtin_amdgcn_s_barrier(); } while (0)

__device__ __forceinline__ int vt_off(int vc, int t) {
  int byte = vc * (VTSTR * 2) + t * 2;
  byte ^= ((vc >> 2) & 7) << 4;   // conflict-free transposed stores, b128-aligned reads
  return byte >> 1;
}
__device__ __forceinline__ int kwt_off(int kd, int t) {
  int byte = kd * (KWSTR * 2) + t * 2;
  byte ^= ((kd >> 2) & 7) << 4;
  return byte >> 1;
}
// A/B fragment, reduction contiguous: elem j -> [row0+(l&15)][kk0+(l>>4)*8+j]
__device__ __forceinline__ bf16x8 frag_row(const bf16* p, int stride, int row0,
                                           int kk0, int lane) {
  int row = row0 + (lane & 15);
  int kk = kk0 + ((lane >> 4) << 3);
  return *(const bf16x8*)(p + row * stride + kk);
}
__device__ __forceinline__ void st4(bf16* p, float a, float b, float c, float d) {
  bf16x4 t;
  t[0] = (bf16)a; t[1] = (bf16)b; t[2] = (bf16)c; t[3] = (bf16)d;
  *(bf16x4*)p = t;  // 8B LDS store
}

__global__ void __launch_bounds__(512, 2)
gla_fused(const float* __restrict__ qg, const float* __restrict__ kg,
          const float* __restrict__ vg, const float* __restrict__ gg,
          float* __restrict__ og)
{
  __shared__ __align__(16) bf16 q_s[2][BT][QSTR];
  __shared__ __align__(16) bf16 k_s[2][BT][QSTR];
  __shared__ __align__(16) bf16 vT_s[2][VSG * VTSTR];  // v^T [vc][t], swizzled
  __shared__ __align__(16) bf16 kwT_s[KD * KWSTR];     // (k*w)^T [kd][t], swizzled
  __shared__ __align__(16) bf16 sh_s[BT][SHSTR];       // gated/masked s-hat [i][j]
  __shared__ __align__(16) bf16 svt_s[VSG][SVSTR];     // h_n slice [vc][kd]
  __shared__ float gc_s[2][BT], w_s[2][BT], egc_s[2][BT], decay_s[2];

  const int tid = threadIdx.x;
  const int wave = tid >> 6;
  const int lane = tid & 63;
  const int bh = blockIdx.x & 63;   // 4 vseg blocks of one bh share an XCD
  const int vseg = blockIdx.x >> 6;

  const int jc = lane & 15;
  const int g4 = lane >> 4;
  const int r0 = g4 << 2;

  const int it = wave & 3;             // q-token tile (s cols, o rows)
  const int nt = wave >> 2;            // o vcol tile
  const int jt0 = (wave < 4) ? 0 : 2;  // k-token tiles {jt0, jt0+1} (s^T rows)

  const size_t qkbase = (size_t)bh * TLEN * KD;
  const size_t gbase = (size_t)bh * TLEN;
  const size_t vbase = (size_t)bh * TLEN * VD + (size_t)vseg * VSG;
  const int vrow = tid >> 3;
  const int vc0 = (tid & 7) << 2;

  float4 qpf[4], kpf[4], vpf;

  auto loadpf = [&](int n) {
    const float4* q4 = (const float4*)(qg + qkbase + (size_t)n * (BT * KD));
    const float4* k4 = (const float4*)(kg + qkbase + (size_t)n * (BT * KD));
#pragma unroll
    for (int i = 0; i < 4; ++i) { qpf[i] = q4[i * 512 + tid]; kpf[i] = k4[i * 512 + tid]; }
    vpf = *(const float4*)(vg + vbase + (size_t)(n * BT + vrow) * VD + vc0);
  };

  auto stage = [&](int buf, int n) {
#pragma unroll
    for (int i = 0; i < 4; ++i) {
      int f4 = i * 512 + tid;
      int row = f4 >> 5;
      int col = (f4 & 31) << 2;
      st4(&q_s[buf][row][col], qpf[i].x, qpf[i].y, qpf[i].z, qpf[i].w);
      st4(&k_s[buf][row][col], kpf[i].x, kpf[i].y, kpf[i].z, kpf[i].w);
    }
    bf16* vt = &vT_s[buf][0];
    vt[vt_off(vc0 + 0, vrow)] = (bf16)vpf.x;
    vt[vt_off(vc0 + 1, vrow)] = (bf16)vpf.y;
    vt[vt_off(vc0 + 2, vrow)] = (bf16)vpf.z;
    vt[vt_off(vc0 + 3, vrow)] = (bf16)vpf.w;
    if (wave == 0) {   // gate scan for chunk n
      float a = gg[gbase + n * BT + lane];
#pragma unroll
      for (int off = 1; off < 64; off <<= 1) {
        float t = __shfl_up(a, off);
        if (lane >= off) a += t;
      }
      float glast = __shfl(a, 63);
      gc_s[buf][lane] = a;
      w_s[buf][lane] = __expf(glast - a);
      egc_s[buf][lane] = __expf(a) * SCALE;
      if (lane == 0) decay_s[buf] = __expf(glast);
    }
  };

  // state: Sa = S[kd = wave*16 + r0+r][vc = jc], Sb = same at vc = 16+jc
  f32x4 Sa = {0.f, 0.f, 0.f, 0.f}, Sb = {0.f, 0.f, 0.f, 0.f};

  loadpf(0);
  stage(0, 0);
  LGKM_BARRIER();

  for (int n = 0; n < NCHUNK; ++n) {
    const int cur = n & 1;

    // ---------- phase 1 ----------
    // kwT = (k * w)^T for chunk n, from kpf regs (still hold chunk n)
#pragma unroll
    for (int i = 0; i < 4; ++i) {
      int f4 = i * 512 + tid;
      int t = f4 >> 5;
      int c0 = (f4 & 31) << 2;
      float wv = w_s[cur][t];
      kwT_s[kwt_off(c0 + 0, t)] = (bf16)(kpf[i].x * wv);
      kwT_s[kwt_off(c0 + 1, t)] = (bf16)(kpf[i].y * wv);
      kwT_s[kwt_off(c0 + 2, t)] = (bf16)(kpf[i].z * wv);
      kwT_s[kwt_off(c0 + 3, t)] = (bf16)(kpf[i].w * wv);
    }
    if (n + 1 < NCHUNK) loadpf(n + 1);  // issue next-chunk HBM loads (in flight across barriers)

    // export pre-update state h_n: b64 stores (lane holds 4 contiguous kd)
    st4(&svt_s[jc][wave * 16 + r0], Sa[0], Sa[1], Sa[2], Sa[3]);
    st4(&svt_s[16 + jc][wave * 16 + r0], Sb[0], Sb[1], Sb[2], Sb[3]);

    bf16x8 af[4];  // q fragments (B for QK^T, A for o_inter — same lane mapping)
#pragma unroll
    for (int ks = 0; ks < 4; ++ks)
      af[ks] = frag_row(&q_s[cur][0][0], QSTR, it * 16, ks * 32, lane);

    // s^T = k q^T (swapped): lane holds rows j = jt*16+r0+r at col i = it*16+jc
    f32x4 sa0 = {0.f,0.f,0.f,0.f}, sa1 = {0.f,0.f,0.f,0.f};
#pragma unroll
    for (int ks = 0; ks < 4; ++ks) {
      bf16x8 a0 = frag_row(&k_s[cur][0][0], QSTR, jt0 * 16, ks * 32, lane);
      bf16x8 a1 = frag_row(&k_s[cur][0][0], QSTR, (jt0 + 1) * 16, ks * 32, lane);
      sa0 = MFMA(a0, af[ks], sa0, 0, 0, 0);
      sa1 = MFMA(a1, af[ks], sa1, 0, 0, 0);
    }
    {
      int i0 = it * 16 + jc;
      float gci = gc_s[cur][i0];
#pragma unroll
      for (int t = 0; t < 2; ++t) {
        f32x4 sv = t ? sa1 : sa0;
        int jb = (jt0 + t) * 16 + r0;
        bf16x4 pk;
#pragma unroll
        for (int r = 0; r < 4; ++r) {
          int j = jb + r;
          float val = (i0 >= j) ? sv[r] * __expf(gci - gc_s[cur][j]) * SCALE : 0.f;
          pk[r] = (bf16)val;
        }
        *(bf16x4*)&sh_s[i0][jb] = pk;  // b64 store, 4 contiguous j
      }
    }
    LGKM_BARRIER();

    // ---------- phase 2 ----------
    {
      f32x4 oacc = {0.f, 0.f, 0.f, 0.f};
#pragma unroll
      for (int ks = 0; ks < 4; ++ks) {  // o_inter = q @ h_n
        bf16x8 b = frag_row(&svt_s[0][0], SVSTR, nt * 16, ks * 32, lane);
        oacc = MFMA(af[ks], b, oacc, 0, 0, 0);
      }
#pragma unroll
      for (int r = 0; r < 4; ++r) oacc[r] *= egc_s[cur][it * 16 + r0 + r];
#pragma unroll
      for (int ks = 0; ks < 2; ++ks) {  // o_intra = s-hat @ v
        bf16x8 a = frag_row(&sh_s[0][0], SHSTR, it * 16, ks * 32, lane);
        bf16x8 b = *(const bf16x8*)(&vT_s[cur][0] + vt_off(nt * 16 + jc, ks * 32 + (g4 << 3)));
        oacc = MFMA(a, b, oacc, 0, 0, 0);
      }
#pragma unroll
      for (int r = 0; r < 4; ++r) {
        int row = it * 16 + r0 + r;
        og[vbase + (size_t)(n * BT + row) * VD + nt * 16 + jc] = oacc[r];
      }
    }
    {
      // S = decay * S + kw^T-weighted outer products (A=kwT, B=vT)
      float dec = decay_s[cur];
#pragma unroll
      for (int r = 0; r < 4; ++r) { Sa[r] *= dec; Sb[r] *= dec; }
#pragma unroll
      for (int ks = 0; ks < 2; ++ks) {
        bf16x8 a = *(const bf16x8*)(kwT_s + kwt_off(wave * 16 + jc, ks * 32 + (g4 << 3)));
        bf16x8 b0 = *(const bf16x8*)(&vT_s[cur][0] + vt_off(jc, ks * 32 + (g4 << 3)));
        bf16x8 b1 = *(const bf16x8*)(&vT_s[cur][0] + vt_off(16 + jc, ks * 32 + (g4 << 3)));
        Sa = MFMA(a, b0, Sa, 0, 0, 0);
        Sb = MFMA(a, b1, Sb, 0, 0, 0);
      }
    }
    if (n + 1 < NCHUNK) stage((n + 1) & 1, n + 1);  // overlaps with MFMAs above
    LGKM_BARRIER();
  }
}

extern "C" void kernel_launch(void* const* d_in, const int* in_sizes, int n_in,
                              void* d_out, int out_size, void* d_ws, size_t ws_size,
                              hipStream_t stream) {
  const float* q = (const float*)d_in[0];
  const float* k = (const float*)d_in[1];
  const float* v = (const float*)d_in[2];
  const float* g = (const float*)d_in[3];
  float* o = (float*)d_out;
  dim3 grid(256);   // 64 (b,h) x 4 v-segments
  dim3 block(512);  // 8 waves
  gla_fused<<<grid, block, 0, stream>>>(q, k, v, g, o);
}